// Round 8
// baseline (523.097 us; speedup 1.0000x reference)
//
#include <hip/hip_runtime.h>
#include <hip/hip_bf16.h>
#include <stdint.h>

#define B_ROWS 2048
#define SEQ 512
#define VOC 30000
#define DMODEL 768
#define K1 1.2f
#define BPAR 0.75f
#define NT 192   // 3 waves; each thread owns one ushort4 (4 bf16) chunk of 768 dims
#define PF 8     // prefetch depth (outstanding global loads per thread)

// ---------------- Kernel 0: zero S (d_ws is not re-poisoned between replays) ----------
__global__ void zero_S(float* __restrict__ S) {
    S[blockIdx.x * 256 + threadIdx.x] = 0.f;
}

// ---------------- Kernel 1: fused transpose + colsum --------------------------------
// W [768][30000] f32 -> Wb [30000][768] bf16, and S[j] = sum_t W[j][t] via per-wave
// partial reduction + atomicAdd (469 atomics per S entry; S only enters the output at
// 1e-10 scale, so f32 atomic-order noise is invisible). 64x64 tiles: 256B read
// segments, 128B write segments, conflict-free padded LDS (stride 66 bf16).
__launch_bounds__(256)
__global__ void prep_W(const float* __restrict__ W, __hip_bfloat16* __restrict__ Wb,
                       float* __restrict__ S) {
    __shared__ __hip_bfloat16 tile[64][66];  // [j_local][t_local], pad->conflict-free cols
    int tBase = blockIdx.x * 64;
    int jBase = blockIdx.y * 64;
    int tx = threadIdx.x;   // 0..63 (one full wave per row)
    int ty = threadIdx.y;   // 0..3

    // read phase: wave ty handles j-rows jBase + jj*4 + ty (256B coalesced reads)
#pragma unroll
    for (int jj = 0; jj < 16; jj++) {
        int j = jBase + jj * 4 + ty;
        int t = tBase + tx;
        float v = (t < VOC) ? W[(size_t)j * VOC + t] : 0.f;
        tile[jj * 4 + ty][tx] = __float2bfloat16(v);
        float s = v;
#pragma unroll
        for (int off = 32; off > 0; off >>= 1) s += __shfl_down(s, off);
        if (tx == 0) atomicAdd(&S[j], s);
    }
    __syncthreads();

    // write phase: wave handles t-rows tBase + tt*4 + ty, lanes sweep j (128B writes)
#pragma unroll
    for (int tt = 0; tt < 16; tt++) {
        int t = tBase + tt * 4 + ty;
        if (t < VOC) {
            Wb[(size_t)t * DMODEL + jBase + tx] = tile[tx][tt * 4 + ty];
        }
    }
}

__device__ __forceinline__ float b2f(unsigned short h) {
    union { uint32_t u; float f; } v; v.u = ((uint32_t)h) << 16; return v.f;
}

// ---------------- Kernel 2: per-row BM25 sparse accumulate + normalize ----------------
// BYTE-IDENTICAL to R7's bm25_main (proven stable: 129 us, FETCH at the 8x46MB floor).
__launch_bounds__(NT, 6)
__global__ void bm25_main(const int* __restrict__ ids, const int* __restrict__ mask,
                          const __hip_bfloat16* __restrict__ Wb, const float* __restrict__ S,
                          float* __restrict__ out) {
    __shared__ int   stoks[SEQ];
    __shared__ float wts[SEQ];
    __shared__ int   nv;
    __shared__ float wred[3];

    int b = blockIdx.x;
    int tid = threadIdx.x;

    if (tid == 0) nv = 0;
    __syncthreads();

    // compact valid tokens (order irrelevant; sort follows)
    for (int i = tid; i < SEQ; i += NT) {
        int id = ids[(size_t)b * SEQ + i];
        int m  = mask[(size_t)b * SEQ + i];
        if (m == 1 && id > 100 && id < VOC) {
            stoks[atomicAdd(&nv, 1)] = id;
        }
    }
    __syncthreads();
    int n = nv;  // == doc_len (positions with multiplicity)

    // pad to 512 with +inf keys
    for (int i = n + tid; i < SEQ; i += NT) stoks[i] = 0x7fffffff;

    // bitonic sort of 512 ints (first barrier inside loop covers padding writes)
    for (int k = 2; k <= SEQ; k <<= 1) {
        for (int j = k >> 1; j > 0; j >>= 1) {
            __syncthreads();
            for (int i = tid; i < SEQ; i += NT) {
                int ixj = i ^ j;
                if (ixj > i) {
                    int a = stoks[i], c = stoks[ixj];
                    if ((a > c) == ((i & k) == 0)) { stoks[i] = c; stoks[ixj] = a; }
                }
            }
        }
    }
    __syncthreads();

    // per-position weight: score(tf)/tf = (K1+1)/(tf + K1*len_norm); tf via sorted runs
    float kln = K1 * fmaxf(1.0f + BPAR * ((float)n / 100.0f - 1.0f), 0.5f);
    for (int i = tid; i < n; i += NT) {
        int t = stoks[i];
        int lo = i; while (lo > 0 && stoks[lo - 1] == t) lo--;
        int hi = i; while (hi < n - 1 && stoks[hi + 1] == t) hi++;
        wts[i] = (K1 + 1.0f) / ((float)(hi - lo + 1) + kln);
    }
    __syncthreads();

    // gather-accumulate in ascending vocab order; thread owns bf16x4 chunk `tid`
    const ushort4* __restrict__ Wb4 = (const ushort4*)Wb;   // row stride DMODEL/4 = 192
    float4 acc = make_float4(0.f, 0.f, 0.f, 0.f);
    int p = 0;
    for (; p + PF <= n; p += PF) {
        ushort4 r[PF];
        float   w[PF];
#pragma unroll
        for (int q = 0; q < PF; q++) {
            r[q] = Wb4[(size_t)stoks[p + q] * (DMODEL / 4) + tid];
            w[q] = wts[p + q];
        }
#pragma unroll
        for (int q = 0; q < PF; q++) {
            acc.x = fmaf(w[q], b2f(r[q].x), acc.x);
            acc.y = fmaf(w[q], b2f(r[q].y), acc.y);
            acc.z = fmaf(w[q], b2f(r[q].z), acc.z);
            acc.w = fmaf(w[q], b2f(r[q].w), acc.w);
        }
    }
    for (; p < n; p++) {
        float w = wts[p];
        ushort4 r = Wb4[(size_t)stoks[p] * (DMODEL / 4) + tid];
        acc.x = fmaf(w, b2f(r.x), acc.x);
        acc.y = fmaf(w, b2f(r.y), acc.y);
        acc.z = fmaf(w, b2f(r.z), acc.z);
        acc.w = fmaf(w, b2f(r.w), acc.w);
    }

    // exact 1e-10 * ones @ W^T term (f32; also guarantees nonzero norm when n == 0)
    float4 s4 = ((const float4*)S)[tid];
    acc.x += 1e-10f * s4.x;
    acc.y += 1e-10f * s4.y;
    acc.z += 1e-10f * s4.z;
    acc.w += 1e-10f * s4.w;

    // L2 norm over 768 dims (intermediate normalize cancels algebraically)
    float ss = acc.x * acc.x + acc.y * acc.y + acc.z * acc.z + acc.w * acc.w;
#pragma unroll
    for (int off = 32; off > 0; off >>= 1) ss += __shfl_down(ss, off);
    if ((tid & 63) == 0) wred[tid >> 6] = ss;
    __syncthreads();
    float inv = 1.0f / sqrtf(wred[0] + wred[1] + wred[2]);

    float4 o;
    o.x = acc.x * inv; o.y = acc.y * inv; o.z = acc.z * inv; o.w = acc.w * inv;
    ((float4*)(out + (size_t)b * DMODEL))[tid] = o;
}

extern "C" void kernel_launch(void* const* d_in, const int* in_sizes, int n_in,
                              void* d_out, int out_size, void* d_ws, size_t ws_size,
                              hipStream_t stream) {
    const int*   ids  = (const int*)d_in[0];
    const int*   mask = (const int*)d_in[1];
    const float* W    = (const float*)d_in[2];
    float* out = (float*)d_out;

    __hip_bfloat16* Wb = (__hip_bfloat16*)d_ws;            // 30000*768*2 = 46,080,000 B
    float* S = (float*)((char*)d_ws + (size_t)VOC * DMODEL * sizeof(__hip_bfloat16));

    zero_S<<<DMODEL / 256, 256, 0, stream>>>(S);

    dim3 pgrid((VOC + 63) / 64, DMODEL / 64);
    dim3 pblock(64, 4);
    prep_W<<<pgrid, pblock, 0, stream>>>(W, Wb, S);

    bm25_main<<<B_ROWS, NT, 0, stream>>>(ids, mask, Wb, S, out);
}

// Round 9
// 189.347 us; speedup vs baseline: 2.7626x; 2.7626x over previous
//
#include <hip/hip_runtime.h>
#include <hip/hip_bf16.h>
#include <stdint.h>

#define B_ROWS 2048
#define SEQ 512
#define VOC 30000
#define DMODEL 768
#define K1 1.2f
#define BPAR 0.75f
#define NT 192   // 3 waves; each thread owns one ushort4 (4 bf16) chunk of 768 dims
#define PF 8     // prefetch depth (outstanding global loads per thread)

// ---------------- Kernel 1: transpose W [768][30000] f32 -> Wb [30000][768] bf16 -------
// 64x64 tile, block (64,4). Pure load->LDS->store (no reductions: R8's fused shfl+atomic
// chain collapsed VGPR to 12 and serialized all loads). Reads: 256B/wave segments.
// Writes: 64 lanes x 2B = one full 128B line per wave (R7's 32-wide version wrote
// half-lines -> RMW traffic -> 2.9 TB/s).
__launch_bounds__(256)
__global__ void transpose_W64(const float* __restrict__ W, __hip_bfloat16* __restrict__ Wb) {
    __shared__ __hip_bfloat16 tile[64][66];  // [j_local][t_local]; 66 -> conflict-free cols
    int tBase = blockIdx.x * 64;
    int jBase = blockIdx.y * 64;
    int tx = threadIdx.x;   // 0..63
    int ty = threadIdx.y;   // 0..3

    // read phase: wave ty reads j-rows jBase + jj*4 + ty, 256B coalesced
#pragma unroll
    for (int jj = 0; jj < 16; jj++) {
        int j = jBase + jj * 4 + ty;
        int t = tBase + tx;
        float v = (t < VOC) ? W[(size_t)j * VOC + t] : 0.f;
        tile[jj * 4 + ty][tx] = __float2bfloat16(v);
    }
    __syncthreads();

    // write phase: wave writes t-rows tBase + tt*4 + ty; lanes sweep j -> full 128B lines
#pragma unroll
    for (int tt = 0; tt < 16; tt++) {
        int t = tBase + tt * 4 + ty;
        if (t < VOC) {
            Wb[(size_t)t * DMODEL + jBase + tx] = tile[tx][tt * 4 + ty];
        }
    }
}

// ---------------- Kernel 2: S[j] = sum_t W[j][t] (exact f32; the 1e-10*ones@W^T term) --
__global__ void colsum_W(const float* __restrict__ W, float* __restrict__ S) {
    int j = blockIdx.x;
    const float* row = W + (size_t)j * VOC;
    float s = 0.f;
    for (int t = threadIdx.x; t < VOC; t += 256) s += row[t];
    __shared__ float red[256];
    red[threadIdx.x] = s;
    __syncthreads();
    for (int off = 128; off > 0; off >>= 1) {
        if (threadIdx.x < off) red[threadIdx.x] += red[threadIdx.x + off];
        __syncthreads();
    }
    if (threadIdx.x == 0) S[j] = red[0];
}

__device__ __forceinline__ float b2f(unsigned short h) {
    union { uint32_t u; float f; } v; v.u = ((uint32_t)h) << 16; return v.f;
}

// ---------------- Kernel 3: per-row BM25 sparse accumulate + normalize ----------------
// BYTE-IDENTICAL to R7's bm25_main (proven stable: 129 us, FETCH at the 8x46MB floor).
__launch_bounds__(NT, 6)
__global__ void bm25_main(const int* __restrict__ ids, const int* __restrict__ mask,
                          const __hip_bfloat16* __restrict__ Wb, const float* __restrict__ S,
                          float* __restrict__ out) {
    __shared__ int   stoks[SEQ];
    __shared__ float wts[SEQ];
    __shared__ int   nv;
    __shared__ float wred[3];

    int b = blockIdx.x;
    int tid = threadIdx.x;

    if (tid == 0) nv = 0;
    __syncthreads();

    // compact valid tokens (order irrelevant; sort follows)
    for (int i = tid; i < SEQ; i += NT) {
        int id = ids[(size_t)b * SEQ + i];
        int m  = mask[(size_t)b * SEQ + i];
        if (m == 1 && id > 100 && id < VOC) {
            stoks[atomicAdd(&nv, 1)] = id;
        }
    }
    __syncthreads();
    int n = nv;  // == doc_len (positions with multiplicity)

    // pad to 512 with +inf keys
    for (int i = n + tid; i < SEQ; i += NT) stoks[i] = 0x7fffffff;

    // bitonic sort of 512 ints (first barrier inside loop covers padding writes)
    for (int k = 2; k <= SEQ; k <<= 1) {
        for (int j = k >> 1; j > 0; j >>= 1) {
            __syncthreads();
            for (int i = tid; i < SEQ; i += NT) {
                int ixj = i ^ j;
                if (ixj > i) {
                    int a = stoks[i], c = stoks[ixj];
                    if ((a > c) == ((i & k) == 0)) { stoks[i] = c; stoks[ixj] = a; }
                }
            }
        }
    }
    __syncthreads();

    // per-position weight: score(tf)/tf = (K1+1)/(tf + K1*len_norm); tf via sorted runs
    float kln = K1 * fmaxf(1.0f + BPAR * ((float)n / 100.0f - 1.0f), 0.5f);
    for (int i = tid; i < n; i += NT) {
        int t = stoks[i];
        int lo = i; while (lo > 0 && stoks[lo - 1] == t) lo--;
        int hi = i; while (hi < n - 1 && stoks[hi + 1] == t) hi++;
        wts[i] = (K1 + 1.0f) / ((float)(hi - lo + 1) + kln);
    }
    __syncthreads();

    // gather-accumulate in ascending vocab order; thread owns bf16x4 chunk `tid`
    const ushort4* __restrict__ Wb4 = (const ushort4*)Wb;   // row stride DMODEL/4 = 192
    float4 acc = make_float4(0.f, 0.f, 0.f, 0.f);
    int p = 0;
    for (; p + PF <= n; p += PF) {
        ushort4 r[PF];
        float   w[PF];
#pragma unroll
        for (int q = 0; q < PF; q++) {
            r[q] = Wb4[(size_t)stoks[p + q] * (DMODEL / 4) + tid];
            w[q] = wts[p + q];
        }
#pragma unroll
        for (int q = 0; q < PF; q++) {
            acc.x = fmaf(w[q], b2f(r[q].x), acc.x);
            acc.y = fmaf(w[q], b2f(r[q].y), acc.y);
            acc.z = fmaf(w[q], b2f(r[q].z), acc.z);
            acc.w = fmaf(w[q], b2f(r[q].w), acc.w);
        }
    }
    for (; p < n; p++) {
        float w = wts[p];
        ushort4 r = Wb4[(size_t)stoks[p] * (DMODEL / 4) + tid];
        acc.x = fmaf(w, b2f(r.x), acc.x);
        acc.y = fmaf(w, b2f(r.y), acc.y);
        acc.z = fmaf(w, b2f(r.z), acc.z);
        acc.w = fmaf(w, b2f(r.w), acc.w);
    }

    // exact 1e-10 * ones @ W^T term (f32; also guarantees nonzero norm when n == 0)
    float4 s4 = ((const float4*)S)[tid];
    acc.x += 1e-10f * s4.x;
    acc.y += 1e-10f * s4.y;
    acc.z += 1e-10f * s4.z;
    acc.w += 1e-10f * s4.w;

    // L2 norm over 768 dims (intermediate normalize cancels algebraically)
    float ss = acc.x * acc.x + acc.y * acc.y + acc.z * acc.z + acc.w * acc.w;
#pragma unroll
    for (int off = 32; off > 0; off >>= 1) ss += __shfl_down(ss, off);
    if ((tid & 63) == 0) wred[tid >> 6] = ss;
    __syncthreads();
    float inv = 1.0f / sqrtf(wred[0] + wred[1] + wred[2]);

    float4 o;
    o.x = acc.x * inv; o.y = acc.y * inv; o.z = acc.z * inv; o.w = acc.w * inv;
    ((float4*)(out + (size_t)b * DMODEL))[tid] = o;
}

extern "C" void kernel_launch(void* const* d_in, const int* in_sizes, int n_in,
                              void* d_out, int out_size, void* d_ws, size_t ws_size,
                              hipStream_t stream) {
    const int*   ids  = (const int*)d_in[0];
    const int*   mask = (const int*)d_in[1];
    const float* W    = (const float*)d_in[2];
    float* out = (float*)d_out;

    __hip_bfloat16* Wb = (__hip_bfloat16*)d_ws;            // 30000*768*2 = 46,080,000 B
    float* S = (float*)((char*)d_ws + (size_t)VOC * DMODEL * sizeof(__hip_bfloat16));

    dim3 tgrid((VOC + 63) / 64, DMODEL / 64);
    dim3 tblock(64, 4);
    transpose_W64<<<tgrid, tblock, 0, stream>>>(W, Wb);

    colsum_W<<<DMODEL, 256, 0, stream>>>(W, S);

    bm25_main<<<B_ROWS, NT, 0, stream>>>(ids, mask, Wb, S, out);
}